// Round 1
// baseline (1085.626 us; speedup 1.0000x reference)
//
#include <hip/hip_runtime.h>

// NPG model: E=4 ensembles, B=16384, STATE=29, ACT=8, HID=512.
// Strategy: prep kernel packs all weights to bf16 in MFMA B-fragment order
// (folding input-norm mu/sigma into layer-0 W/b); fused kernel does the whole
// model per 32-batch-row block (leg MLP 4 passes + pose MLP 1 pass, per
// ensemble), h1/h2 staged in LDS, 16x16x32 bf16 MFMA, fp32 epilogues.

#define E_ 4
#define B_ 16384

typedef float f32x4 __attribute__((ext_vector_type(4)));
typedef __bf16 bf16x8 __attribute__((ext_vector_type(8)));

__device__ __forceinline__ f32x4 mfma16(bf16x8 a, bf16x8 b, f32x4 c) {
  return __builtin_amdgcn_mfma_f32_16x16x32_bf16(a, b, c, 0, 0, 0);
}

// leg-format position mapping: output slot 13+k <- leg-block ib, component j
__device__ __forceinline__ void fmt_map(int k, int& ib, int& j) {
  if (k < 8) { ib = k >> 1; j = (k & 1) ? 2 : 0; }
  else { int k8 = k - 8; ib = k8 >> 1; j = (k8 & 1) ? 3 : 1; }
}

// ---------------- prep: pack weights into bf16 MFMA-B-fragment order --------
// Packed layout for W (K x N): tiles (nt,kt) of 32x16; element index
// ((nt*KT + kt)*64 + lane)*8 + j  holds  W[kt*32 + (lane>>4)*8 + j][nt*16 + (lane&15)]
__device__ __forceinline__ void pack_one(int idx, int per_e, int KT, int Kreal,
                                         int Nsrc, int Nval,
                                         const float* __restrict__ src,
                                         const float* __restrict__ sigma,
                                         __bf16* __restrict__ dst)
{
  int e = idx / per_e;
  int rem = idx - e * per_e;
  int g = rem >> 9;            // nt*KT + kt
  int nt = g / KT;
  int kt = g - nt * KT;
  int li = rem & 511;
  int lane = li >> 3, j = li & 7;
  int k = kt * 32 + (lane >> 4) * 8 + j;
  int n = nt * 16 + (lane & 15);
  float v = 0.f;
  if (k < Kreal && n < Nval) {
    v = src[(size_t)e * Kreal * Nsrc + (size_t)k * Nsrc + n];
    if (sigma) v *= 1.f / (sigma[k] + 1e-8f);   // fold input normalization
  }
  dst[idx] = (__bf16)v;
}

__global__ void prep_kernel(const float* __restrict__ wl0, const float* __restrict__ wl1,
                            const float* __restrict__ wl2, const float* __restrict__ wp0,
                            const float* __restrict__ wp1, const float* __restrict__ wp2,
                            const float* __restrict__ bl0, const float* __restrict__ bp0,
                            const float* __restrict__ mu_leg, const float* __restrict__ sigma_leg,
                            const float* __restrict__ mu_pose, const float* __restrict__ sigma_pose,
                            __bf16* __restrict__ WL0p, __bf16* __restrict__ WL1p,
                            __bf16* __restrict__ WL2p, __bf16* __restrict__ WP0p,
                            __bf16* __restrict__ WP1p, __bf16* __restrict__ WP2p,
                            float* __restrict__ bl0f, float* __restrict__ bp0f)
{
  const int S0 = 65536, S1 = 1048576, S2 = 32768;
  const int total = 2 * (S0 + S1 + S2) + 4096;
  for (int idx0 = blockIdx.x * blockDim.x + threadIdx.x; idx0 < total;
       idx0 += gridDim.x * blockDim.x) {
    int x = idx0;
    if (x < S0)              { pack_one(x, 16384, 1, 6, 512, 512, wl0, sigma_leg, WL0p); }
    else if ((x -= S0) < S1) { pack_one(x, 262144, 16, 512, 512, 512, wl1, nullptr, WL1p); }
    else if ((x -= S1) < S2) { pack_one(x, 8192, 16, 512, 8, 8, wl2, nullptr, WL2p); }
    else if ((x -= S2) < S0) { pack_one(x, 16384, 1, 29, 512, 512, wp0, sigma_pose, WP0p); }
    else if ((x -= S0) < S1) { pack_one(x, 262144, 16, 512, 512, 512, wp1, nullptr, WP1p); }
    else if ((x -= S1) < S2) { pack_one(x, 8192, 16, 512, 26, 16, wp2, nullptr, WP2p); }
    else {
      x -= S2;  // bias folds: b0' = b0 - sum_k mu[k]/(sigma[k]+eps) * W0[k,:]
      if (x < 2048) {
        int e = x >> 9, n = x & 511;
        float s = bl0[e * 512 + n];
        #pragma unroll
        for (int k = 0; k < 6; ++k)
          s -= mu_leg[k] / (sigma_leg[k] + 1e-8f) * wl0[(e * 6 + k) * 512 + n];
        bl0f[e * 512 + n] = s;
      } else {
        x -= 2048;
        int e = x >> 9, n = x & 511;
        float s = bp0[e * 512 + n];
        for (int k = 0; k < 29; ++k)
          s -= mu_pose[k] / (sigma_pose[k] + 1e-8f) * wp0[(e * 29 + k) * 512 + n];
        bp0f[e * 512 + n] = s;
      }
    }
  }
}

// ---------------- fused model kernel ----------------------------------------
// 512 blocks x 512 threads; block owns 32 batch rows (b0..b0+31).
// Per ensemble: 4 leg passes (8 batch x 4 leg-blocks = 32 rows each) + 1 pose
// pass (32 rows). Each pass: layer0 (K=32 padded) -> h1 LDS -> layer1 in 4
// col-chunks of 128 with fused layer2 via h2-chunk LDS round-trip.
__global__ __launch_bounds__(512) void fused_kernel(
    const float* __restrict__ state, const float* __restrict__ act,
    const float* __restrict__ bl1, const float* __restrict__ bl2,
    const float* __restrict__ bp1, const float* __restrict__ bp2,
    const float* __restrict__ mu_t_leg, const float* __restrict__ sigma_t_leg,
    const float* __restrict__ mu_t_pose, const float* __restrict__ sigma_t_pose,
    const __bf16* __restrict__ WL0p, const __bf16* __restrict__ WL1p,
    const __bf16* __restrict__ WL2p, const __bf16* __restrict__ WP0p,
    const __bf16* __restrict__ WP1p, const __bf16* __restrict__ WP2p,
    const float* __restrict__ bl0f, const float* __restrict__ bp0f,
    float* __restrict__ out)
{
  __shared__ alignas(16) __bf16 h1[32 * 520];    // 32 rows x 512 (+8 pad)
  __shared__ alignas(16) __bf16 h2c[32 * 136];   // 32 rows x 128 (+8 pad)
  __shared__ alignas(16) __bf16 a0s[32 * 40];    // 32 rows x 32 (+8 pad)
  __shared__ float ldiff[32][16];                // per-batch-row leg diffs
  __shared__ float outacc[32 * 32];              // output accum (29 used)

  const int tid = threadIdx.x;
  const int wv = tid >> 6;        // wave 0..7
  const int lane = tid & 63;
  const int quad = lane >> 4;
  const int l16 = lane & 15;
  const int b0 = blockIdx.x * 32;

  for (int i = tid; i < 32 * 32; i += 512) outacc[i] = 0.f;
  __syncthreads();

  for (int e = 0; e < E_; ++e) {
    const float* se = state + (size_t)e * B_ * 29;
    const float* ae = act + (size_t)e * B_ * 8;

    for (int pass = 0; pass < 5; ++pass) {
      const bool is_leg = (pass < 4);

      // ---- build A0 (32 x 32, stride 40), raw features (norm folded into W0)
      for (int i = tid; i < 32 * 32; i += 512) {
        int r = i >> 5, c = i & 31;
        float v = 0.f;
        if (is_leg) {
          if (c < 6) {
            int ib = r >> 3;                  // leg block 0..3
            int b = b0 + pass * 8 + (r & 7);  // batch row
            const float* sp = se + (size_t)b * 29;
            if (c == 0) v = sp[13 + 2 * ib];
            else if (c == 1) v = sp[21 + 2 * ib];
            else if (c == 2) v = sp[14 + 2 * ib];
            else if (c == 3) v = sp[22 + 2 * ib];
            else if (c == 4) v = ae[(size_t)b * 8 + 2 * ib];
            else v = ae[(size_t)b * 8 + 2 * ib + 1];
          }
        } else {
          if (c < 13) v = se[(size_t)(b0 + r) * 29 + c];
          else if (c < 29) {
            int ib, j; fmt_map(c - 13, ib, j);
            v = ldiff[r][ib * 4 + j];
          }
        }
        a0s[r * 40 + c] = (__bf16)v;
      }
      __syncthreads();

      const __bf16* W0 = (is_leg ? WL0p : WP0p) + (size_t)e * 16384;
      const __bf16* W1 = (is_leg ? WL1p : WP1p) + (size_t)e * 262144;
      const __bf16* W2 = (is_leg ? WL2p : WP2p) + (size_t)e * 8192;
      const float* b0v = (is_leg ? bl0f : bp0f) + e * 512;
      const float* b1v = (is_leg ? bl1 : bp1) + e * 512;

      // ---- layer0: h1(32x512) = relu(A0 @ W0 + b0')
      {
        int rt0 = wv >> 2;                       // row-tile 0..1
        bf16x8 afr = *(const bf16x8*)&a0s[(rt0 * 16 + l16) * 40 + quad * 8];
        #pragma unroll
        for (int tt = 0; tt < 8; ++tt) {
          int ct = (wv & 3) * 8 + tt;            // col-tile 0..31
          bf16x8 bfr = *(const bf16x8*)(W0 + ((size_t)ct * 64 + lane) * 8);
          float bias = b0v[ct * 16 + l16];
          f32x4 acc = {bias, bias, bias, bias};
          acc = mfma16(afr, bfr, acc);
          int col = ct * 16 + l16;
          #pragma unroll
          for (int r = 0; r < 4; ++r)
            h1[(rt0 * 16 + quad * 4 + r) * 520 + col] = (__bf16)fmaxf(acc[r], 0.f);
        }
      }
      __syncthreads();

      // layer2 output accumulator: waves 0..1 hold row-tile wv (16 rows x 16 cols)
      f32x4 oacc = {0.f, 0.f, 0.f, 0.f};
      if (wv < 2) {
        float bv = 0.f;
        if (is_leg) { if (l16 < 8) bv = bl2[e * 8 + l16]; }
        else bv = bp2[e * 26 + l16];             // l16<16<26
        oacc = (f32x4){bv, bv, bv, bv};
      }

      // ---- layer1 (K=512) in 4 col-chunks of 128, layer2 fused per chunk
      const int rt = wv >> 2;                    // row-tile 0..1
      const int ctb = (wv & 3) * 2;              // col-tile pair within chunk
      for (int cc = 0; cc < 4; ++cc) {
        f32x4 acc[2];
        #pragma unroll
        for (int i = 0; i < 2; ++i) {
          float bias = b1v[cc * 128 + (ctb + i) * 16 + l16];
          acc[i] = (f32x4){bias, bias, bias, bias};
        }
        #pragma unroll 4
        for (int k0 = 0; k0 < 512; k0 += 32) {
          bf16x8 afr = *(const bf16x8*)&h1[(rt * 16 + l16) * 520 + k0 + quad * 8];
          int kt = k0 >> 5;
          #pragma unroll
          for (int i = 0; i < 2; ++i) {
            int nt = cc * 8 + ctb + i;
            bf16x8 bfr = *(const bf16x8*)(W1 + (((size_t)nt * 16 + kt) * 64 + lane) * 8);
            acc[i] = mfma16(afr, bfr, acc[i]);
          }
        }
        __syncthreads();   // prior chunk's layer2 reads of h2c are done
        #pragma unroll
        for (int i = 0; i < 2; ++i) {
          int colb = (ctb + i) * 16 + l16;
          #pragma unroll
          for (int r = 0; r < 4; ++r)
            h2c[(rt * 16 + quad * 4 + r) * 136 + colb] = (__bf16)fmaxf(acc[i][r], 0.f);
        }
        __syncthreads();
        if (wv < 2) {      // layer2: out(32x16) += h2chunk @ W2[cc*128.., :]
          #pragma unroll
          for (int k2 = 0; k2 < 4; ++k2) {
            bf16x8 afr2 = *(const bf16x8*)&h2c[(wv * 16 + l16) * 136 + k2 * 32 + quad * 8];
            bf16x8 bfr2 = *(const bf16x8*)(W2 + ((size_t)(cc * 4 + k2) * 64 + lane) * 8);
            oacc = mfma16(afr2, bfr2, oacc);
          }
        }
      }

      // ---- epilogue (fp32): C/D layout row=(quad*4+reg), col=l16
      if (wv < 2) {
        if (is_leg) {
          if (l16 < 4) {
            float sc = sigma_t_leg[l16] + 1e-8f;
            float mv = mu_t_leg[l16];
            #pragma unroll
            for (int r = 0; r < 4; ++r) {
              int row = wv * 16 + quad * 4 + r;          // 0..31 = ib*8 + t
              ldiff[pass * 8 + (row & 7)][(row >> 3) * 4 + l16] = oacc[r] * sc + mv;
            }
          }
        } else {
          if (l16 < 13) {
            float sc = sigma_t_pose[l16] + 1e-8f;
            float mv = mu_t_pose[l16];
            #pragma unroll
            for (int r = 0; r < 4; ++r) {
              int row = wv * 16 + quad * 4 + r;
              outacc[row * 32 + l16] += oacc[r] * sc + mv + se[(size_t)(b0 + row) * 29 + l16];
            }
          }
        }
      }
      __syncthreads();
    } // pass

    // legs portion of output: next_state_legs = state + formatted diff
    for (int i = tid; i < 32 * 16; i += 512) {
      int t = i >> 4, k = i & 15;
      int ib, j; fmt_map(k, ib, j);
      outacc[t * 32 + 13 + k] += se[(size_t)(b0 + t) * 29 + 13 + k] + ldiff[t][ib * 4 + j];
    }
    __syncthreads();
  } // e

  // mean over ensembles, write (B,29) fp32
  for (int i = tid; i < 32 * 29; i += 512) {
    int t = i / 29, c = i - t * 29;
    out[(size_t)(b0 + t) * 29 + c] = 0.25f * outacc[t * 32 + c];
  }
}

// ---------------- launch ----------------------------------------------------
extern "C" void kernel_launch(void* const* d_in, const int* in_sizes, int n_in,
                              void* d_out, int out_size, void* d_ws, size_t ws_size,
                              hipStream_t stream) {
  const float* state = (const float*)d_in[0];
  const float* act = (const float*)d_in[1];
  const float* wl0 = (const float*)d_in[2];
  const float* bl0 = (const float*)d_in[3];
  const float* wl1 = (const float*)d_in[4];
  const float* bl1 = (const float*)d_in[5];
  const float* wl2 = (const float*)d_in[6];
  const float* bl2 = (const float*)d_in[7];
  const float* wp0 = (const float*)d_in[8];
  const float* bp0 = (const float*)d_in[9];
  const float* wp1 = (const float*)d_in[10];
  const float* bp1 = (const float*)d_in[11];
  const float* wp2 = (const float*)d_in[12];
  const float* bp2 = (const float*)d_in[13];
  const float* mu_leg = (const float*)d_in[14];
  const float* sigma_leg = (const float*)d_in[15];
  const float* mu_pose = (const float*)d_in[16];
  const float* sigma_pose = (const float*)d_in[17];
  const float* mu_t_leg = (const float*)d_in[18];
  const float* sigma_t_leg = (const float*)d_in[19];
  const float* mu_t_pose = (const float*)d_in[20];
  const float* sigma_t_pose = (const float*)d_in[21];
  float* out = (float*)d_out;

  // workspace layout (bf16 packed weights + folded biases), ~4.6 MB total
  char* ws = (char*)d_ws;
  __bf16* WL0p = (__bf16*)(ws);
  __bf16* WL1p = (__bf16*)(ws + 131072);
  __bf16* WL2p = (__bf16*)(ws + 2228224);
  __bf16* WP0p = (__bf16*)(ws + 2293760);
  __bf16* WP1p = (__bf16*)(ws + 2424832);
  __bf16* WP2p = (__bf16*)(ws + 4521984);
  float* bl0f = (float*)(ws + 4587520);
  float* bp0f = (float*)(ws + 4595712);

  prep_kernel<<<512, 256, 0, stream>>>(wl0, wl1, wl2, wp0, wp1, wp2, bl0, bp0,
                                       mu_leg, sigma_leg, mu_pose, sigma_pose,
                                       WL0p, WL1p, WL2p, WP0p, WP1p, WP2p,
                                       bl0f, bp0f);
  fused_kernel<<<512, 512, 0, stream>>>(state, act, bl1, bl2, bp1, bp2,
                                        mu_t_leg, sigma_t_leg, mu_t_pose, sigma_t_pose,
                                        WL0p, WL1p, WL2p, WP0p, WP1p, WP2p,
                                        bl0f, bp0f, out);
}

// Round 2
// 370.078 us; speedup vs baseline: 2.9335x; 2.9335x over previous
//
#include <hip/hip_runtime.h>

// NPG model: E=4 ensembles, B=16384, STATE=29, ACT=8, HID=512.
// R2: register-blocked fused MLP. Block = 64 batch rows (256 blocks, 512 thr,
// 1 block/CU, ~155KB LDS). Per ensemble: 2 leg passes of 128 rows + 1 pose
// pass of 64 rows. Layer1 wave tile = 64 rows x 32 cols (4rt x 2ct, 8 acc):
// per k-step 4 LDS A-frags + 2 L2 B-frags -> 8 MFMA (0.25KB L2/MFMA).
// Layer2 fused via 64-row h2 LDS staging; leg out -> ldiff, pose out -> regs.

#define E_ 4
#define B_ 16384
#define H1S 520   // h1 row stride (bf16 elems), 16B-aligned, 2-way-bank-free
#define H2S 136   // h2 staging row stride
#define A0S 40    // a0 row stride

typedef float f32x4 __attribute__((ext_vector_type(4)));
typedef __bf16 bf16x8 __attribute__((ext_vector_type(8)));

__device__ __forceinline__ f32x4 mfma16(bf16x8 a, bf16x8 b, f32x4 c) {
  return __builtin_amdgcn_mfma_f32_16x16x32_bf16(a, b, c, 0, 0, 0);
}

// leg-format position mapping: output slot 13+k <- leg-block ib, component j
__device__ __forceinline__ void fmt_map(int k, int& ib, int& j) {
  if (k < 8) { ib = k >> 1; j = (k & 1) ? 2 : 0; }
  else { int k8 = k - 8; ib = k8 >> 1; j = (k8 & 1) ? 3 : 1; }
}

// ---------------- prep: pack weights into bf16 MFMA-B-fragment order --------
// Packed W (K x N): tiles (nt,kt) of 32x16; element ((nt*KT+kt)*64+lane)*8+j
// holds W[kt*32 + (lane>>4)*8 + j][nt*16 + (lane&15)]
__device__ __forceinline__ void pack_one(int idx, int per_e, int KT, int Kreal,
                                         int Nsrc, int Nval,
                                         const float* __restrict__ src,
                                         const float* __restrict__ sigma,
                                         __bf16* __restrict__ dst)
{
  int e = idx / per_e;
  int rem = idx - e * per_e;
  int g = rem >> 9;            // nt*KT + kt
  int nt = g / KT;
  int kt = g - nt * KT;
  int li = rem & 511;
  int lane = li >> 3, j = li & 7;
  int k = kt * 32 + (lane >> 4) * 8 + j;
  int n = nt * 16 + (lane & 15);
  float v = 0.f;
  if (k < Kreal && n < Nval) {
    v = src[(size_t)e * Kreal * Nsrc + (size_t)k * Nsrc + n];
    if (sigma) v *= 1.f / (sigma[k] + 1e-8f);   // fold input normalization
  }
  dst[idx] = (__bf16)v;
}

__global__ void prep_kernel(const float* __restrict__ wl0, const float* __restrict__ wl1,
                            const float* __restrict__ wl2, const float* __restrict__ wp0,
                            const float* __restrict__ wp1, const float* __restrict__ wp2,
                            const float* __restrict__ bl0, const float* __restrict__ bp0,
                            const float* __restrict__ mu_leg, const float* __restrict__ sigma_leg,
                            const float* __restrict__ mu_pose, const float* __restrict__ sigma_pose,
                            __bf16* __restrict__ WL0p, __bf16* __restrict__ WL1p,
                            __bf16* __restrict__ WL2p, __bf16* __restrict__ WP0p,
                            __bf16* __restrict__ WP1p, __bf16* __restrict__ WP2p,
                            float* __restrict__ bl0f, float* __restrict__ bp0f)
{
  const int S0 = 65536, S1 = 1048576, S2 = 32768;
  const int total = 2 * (S0 + S1 + S2) + 4096;
  for (int idx0 = blockIdx.x * blockDim.x + threadIdx.x; idx0 < total;
       idx0 += gridDim.x * blockDim.x) {
    int x = idx0;
    if (x < S0)              { pack_one(x, 16384, 1, 6, 512, 512, wl0, sigma_leg, WL0p); }
    else if ((x -= S0) < S1) { pack_one(x, 262144, 16, 512, 512, 512, wl1, nullptr, WL1p); }
    else if ((x -= S1) < S2) { pack_one(x, 8192, 16, 512, 8, 8, wl2, nullptr, WL2p); }
    else if ((x -= S2) < S0) { pack_one(x, 16384, 1, 29, 512, 512, wp0, sigma_pose, WP0p); }
    else if ((x -= S0) < S1) { pack_one(x, 262144, 16, 512, 512, 512, wp1, nullptr, WP1p); }
    else if ((x -= S1) < S2) { pack_one(x, 8192, 16, 512, 26, 16, wp2, nullptr, WP2p); }
    else {
      x -= S2;  // bias folds: b0' = b0 - sum_k mu[k]/(sigma[k]+eps) * W0[k,:]
      if (x < 2048) {
        int e = x >> 9, n = x & 511;
        float s = bl0[e * 512 + n];
        #pragma unroll
        for (int k = 0; k < 6; ++k)
          s -= mu_leg[k] / (sigma_leg[k] + 1e-8f) * wl0[(e * 6 + k) * 512 + n];
        bl0f[e * 512 + n] = s;
      } else {
        x -= 2048;
        int e = x >> 9, n = x & 511;
        float s = bp0[e * 512 + n];
        for (int k = 0; k < 29; ++k)
          s -= mu_pose[k] / (sigma_pose[k] + 1e-8f) * wp0[(e * 29 + k) * 512 + n];
        bp0f[e * 512 + n] = s;
      }
    }
  }
}

// ---------------- fused model kernel ----------------------------------------
__global__ __launch_bounds__(512) void fused_kernel(
    const float* __restrict__ state, const float* __restrict__ act,
    const float* __restrict__ bl1, const float* __restrict__ bl2,
    const float* __restrict__ bp1, const float* __restrict__ bp2,
    const float* __restrict__ mu_t_leg, const float* __restrict__ sigma_t_leg,
    const float* __restrict__ mu_t_pose, const float* __restrict__ sigma_t_pose,
    const __bf16* __restrict__ WL0p, const __bf16* __restrict__ WL1p,
    const __bf16* __restrict__ WL2p, const __bf16* __restrict__ WP0p,
    const __bf16* __restrict__ WP1p, const __bf16* __restrict__ WP2p,
    const float* __restrict__ bl0f, const float* __restrict__ bp0f,
    float* __restrict__ out)
{
  __shared__ alignas(16) __bf16 h1[128 * H1S];   // 133120 B
  __shared__ alignas(16) __bf16 h2c[64 * H2S];   // 17408 B (union with a0)
  __shared__ float ldiff[64][16];                // 4096 B
  __shared__ float legacc[64][16];               // 4096 B  -> total 158 KB
  __bf16* a0s = h2c;                             // a0 <=128*40=10240B, fits

  const int tid = threadIdx.x;
  const int wv = tid >> 6;        // wave 0..7
  const int lane = tid & 63;
  const int quad = lane >> 4;
  const int l16 = lane & 15;
  const int b0 = blockIdx.x * 64;

  for (int i = tid; i < 64 * 16; i += 512) ((float*)legacc)[i] = 0.f;
  f32x4 posacc = {0.f, 0.f, 0.f, 0.f};
  __syncthreads();

  for (int e = 0; e < E_; ++e) {
    const float* se = state + (size_t)e * B_ * 29;
    const float* ae = act + (size_t)e * B_ * 8;

    // ================= leg MLP: 2 passes of 128 leg rows =================
    for (int half = 0; half < 2; ++half) {
      __syncthreads();   // h2c/a0 region free (prior readers done)
      // ---- a0 build: 128 rows (ib*32+t) x 32 cols (6 real)
      for (int i = tid; i < 128 * 32; i += 512) {
        int r = i >> 5, c = i & 31;
        float v = 0.f;
        if (c < 6) {
          int ib = r >> 5;
          int b = b0 + half * 32 + (r & 31);
          const float* sp = se + (size_t)b * 29;
          if (c == 0) v = sp[13 + 2 * ib];
          else if (c == 1) v = sp[21 + 2 * ib];
          else if (c == 2) v = sp[14 + 2 * ib];
          else if (c == 3) v = sp[22 + 2 * ib];
          else if (c == 4) v = ae[(size_t)b * 8 + 2 * ib];
          else v = ae[(size_t)b * 8 + 2 * ib + 1];
        }
        a0s[r * A0S + c] = (__bf16)v;
      }
      __syncthreads();

      // ---- layer0: h1(128x512) = relu(A0 @ W0 + b0'); wave owns 4 col-tiles
      {
        const __bf16* W0 = WL0p + (size_t)e * 16384;
        const float* b0v = bl0f + e * 512;
        bf16x8 bfr[4]; float bs[4];
        #pragma unroll
        for (int i = 0; i < 4; ++i) {
          int ct = wv * 4 + i;
          bfr[i] = *(const bf16x8*)(W0 + ((size_t)ct * 64 + lane) * 8);
          bs[i] = b0v[ct * 16 + l16];
        }
        for (int rt = 0; rt < 8; ++rt) {
          bf16x8 afr = *(const bf16x8*)&a0s[(rt * 16 + l16) * A0S + quad * 8];
          #pragma unroll
          for (int i = 0; i < 4; ++i) {
            f32x4 acc = {bs[i], bs[i], bs[i], bs[i]};
            acc = mfma16(afr, bfr[i], acc);
            int col = (wv * 4 + i) * 16 + l16;
            #pragma unroll
            for (int r = 0; r < 4; ++r)
              h1[(rt * 16 + quad * 4 + r) * H1S + col] = (__bf16)fmaxf(acc[r], 0.f);
          }
        }
      }
      __syncthreads();

      // ---- layer1 (128x512x512) + fused layer2; wave tile 64r x 32c
      const __bf16* W1 = WL1p + (size_t)e * 262144;
      const __bf16* W2 = WL2p + (size_t)e * 8192;
      const float* b1v = bl1 + e * 512;
      const int rg = wv >> 2, cg = wv & 3;
      float bv2 = (l16 < 8) ? bl2[e * 8 + l16] : 0.f;
      f32x4 oacc = {bv2, bv2, bv2, bv2};     // wave wv owns row-tile wv (l2)

      for (int cc = 0; cc < 4; ++cc) {
        f32x4 acc[4][2];
        #pragma unroll
        for (int ct = 0; ct < 2; ++ct) {
          float bias = b1v[cc * 128 + cg * 32 + ct * 16 + l16];
          #pragma unroll
          for (int i = 0; i < 4; ++i) acc[i][ct] = (f32x4){bias, bias, bias, bias};
        }
        const __bf16* Wc = W1 + (size_t)(cc * 8 + cg * 2) * 8192;
        #pragma unroll 4
        for (int kt = 0; kt < 16; ++kt) {
          bf16x8 afr[4];
          #pragma unroll
          for (int i = 0; i < 4; ++i)
            afr[i] = *(const bf16x8*)&h1[(rg * 64 + i * 16 + l16) * H1S + kt * 32 + quad * 8];
          #pragma unroll
          for (int ct = 0; ct < 2; ++ct) {
            bf16x8 bfr = *(const bf16x8*)(Wc + (((size_t)ct * 16 + kt) * 64 + lane) * 8);
            #pragma unroll
            for (int i = 0; i < 4; ++i) acc[i][ct] = mfma16(afr[i], bfr, acc[i][ct]);
          }
        }
        // stage h2 in two 64-row halves; owners accumulate layer2
        #pragma unroll
        for (int hh = 0; hh < 2; ++hh) {
          __syncthreads();
          if (rg == hh) {
            #pragma unroll
            for (int i = 0; i < 4; ++i)
              #pragma unroll
              for (int ct = 0; ct < 2; ++ct)
                #pragma unroll
                for (int r = 0; r < 4; ++r)
                  h2c[(i * 16 + quad * 4 + r) * H2S + cg * 32 + ct * 16 + l16] =
                      (__bf16)fmaxf(acc[i][ct][r], 0.f);
          }
          __syncthreads();
          if ((wv >> 2) == hh) {
            #pragma unroll
            for (int k2 = 0; k2 < 4; ++k2) {
              bf16x8 afr2 = *(const bf16x8*)&h2c[((wv & 3) * 16 + l16) * H2S + k2 * 32 + quad * 8];
              bf16x8 bfr2 = *(const bf16x8*)(W2 + ((size_t)(cc * 4 + k2) * 64 + lane) * 8);
              oacc = mfma16(afr2, bfr2, oacc);
            }
          }
        }
      }
      // ---- leg epilogue: ldiff (only first 4 outputs used)
      if (l16 < 4) {
        float sc = sigma_t_leg[l16] + 1e-8f;
        float mv = mu_t_leg[l16];
        #pragma unroll
        for (int r = 0; r < 4; ++r) {
          int L = wv * 16 + quad * 4 + r;    // leg row = ib*32 + t
          ldiff[half * 32 + (L & 31)][(L >> 5) * 4 + l16] = oacc[r] * sc + mv;
        }
      }
    } // half

    // ================= pose MLP: 64 rows =================
    __syncthreads();   // ldiff ready, h2c free
    for (int i = tid; i < 64 * 32; i += 512) {
      int t = i >> 5, c = i & 31;
      float v = 0.f;
      if (c < 13) v = se[(size_t)(b0 + t) * 29 + c];
      else if (c < 29) { int ib, j; fmt_map(c - 13, ib, j); v = ldiff[t][ib * 4 + j]; }
      a0s[t * A0S + c] = (__bf16)v;
    }
    for (int i = tid; i < 64 * 16; i += 512) {   // legs output accumulation
      int t = i >> 4, k = i & 15;
      int ib, j; fmt_map(k, ib, j);
      legacc[t][k] += se[(size_t)(b0 + t) * 29 + 13 + k] + ldiff[t][ib * 4 + j];
    }
    __syncthreads();

    // ---- pose layer0: h1(64x512)
    {
      const __bf16* W0 = WP0p + (size_t)e * 16384;
      const float* b0v = bp0f + e * 512;
      bf16x8 bfr[4]; float bs[4];
      #pragma unroll
      for (int i = 0; i < 4; ++i) {
        int ct = wv * 4 + i;
        bfr[i] = *(const bf16x8*)(W0 + ((size_t)ct * 64 + lane) * 8);
        bs[i] = b0v[ct * 16 + l16];
      }
      for (int rt = 0; rt < 4; ++rt) {
        bf16x8 afr = *(const bf16x8*)&a0s[(rt * 16 + l16) * A0S + quad * 8];
        #pragma unroll
        for (int i = 0; i < 4; ++i) {
          f32x4 acc = {bs[i], bs[i], bs[i], bs[i]};
          acc = mfma16(afr, bfr[i], acc);
          int col = (wv * 4 + i) * 16 + l16;
          #pragma unroll
          for (int r = 0; r < 4; ++r)
            h1[(rt * 16 + quad * 4 + r) * H1S + col] = (__bf16)fmaxf(acc[r], 0.f);
        }
      }
    }
    __syncthreads();

    // ---- pose layer1 (64x512x512) + fused layer2 (N=13 -> 1 col-tile)
    {
      const __bf16* W1 = WP1p + (size_t)e * 262144;
      const __bf16* W2 = WP2p + (size_t)e * 8192;
      const float* b1v = bp1 + e * 512;
      float bvp = bp2[e * 26 + l16];
      f32x4 po = {bvp, bvp, bvp, bvp};       // waves 0..3 own row-tiles 0..3

      for (int cc2 = 0; cc2 < 2; ++cc2) {
        f32x4 acc[4][2];
        #pragma unroll
        for (int ct = 0; ct < 2; ++ct) {
          float bias = b1v[cc2 * 256 + wv * 32 + ct * 16 + l16];
          #pragma unroll
          for (int i = 0; i < 4; ++i) acc[i][ct] = (f32x4){bias, bias, bias, bias};
        }
        const __bf16* Wc = W1 + (size_t)(cc2 * 16 + wv * 2) * 8192;
        #pragma unroll 4
        for (int kt = 0; kt < 16; ++kt) {
          bf16x8 afr[4];
          #pragma unroll
          for (int i = 0; i < 4; ++i)
            afr[i] = *(const bf16x8*)&h1[(i * 16 + l16) * H1S + kt * 32 + quad * 8];
          #pragma unroll
          for (int ct = 0; ct < 2; ++ct) {
            bf16x8 bfr = *(const bf16x8*)(Wc + (((size_t)ct * 16 + kt) * 64 + lane) * 8);
            #pragma unroll
            for (int i = 0; i < 4; ++i) acc[i][ct] = mfma16(afr[i], bfr, acc[i][ct]);
          }
        }
        // stage in two 128-col halves (cols cg<4 then cg>=4)
        #pragma unroll
        for (int hh = 0; hh < 2; ++hh) {
          __syncthreads();
          if ((wv >> 2) == hh) {
            int cgl = wv & 3;
            #pragma unroll
            for (int i = 0; i < 4; ++i)
              #pragma unroll
              for (int ct = 0; ct < 2; ++ct)
                #pragma unroll
                for (int r = 0; r < 4; ++r)
                  h2c[(i * 16 + quad * 4 + r) * H2S + cgl * 32 + ct * 16 + l16] =
                      (__bf16)fmaxf(acc[i][ct][r], 0.f);
          }
          __syncthreads();
          if (wv < 4) {
            #pragma unroll
            for (int k2 = 0; k2 < 4; ++k2) {
              bf16x8 afr2 = *(const bf16x8*)&h2c[(wv * 16 + l16) * H2S + k2 * 32 + quad * 8];
              bf16x8 bfr2 = *(const bf16x8*)(W2 + ((size_t)(cc2 * 8 + hh * 4 + k2) * 64 + lane) * 8);
              po = mfma16(afr2, bfr2, po);
            }
          }
        }
      }
      // pose epilogue: accumulate into registers across ensembles
      if (wv < 4 && l16 < 13) {
        float sc = sigma_t_pose[l16] + 1e-8f;
        float mv = mu_t_pose[l16];
        #pragma unroll
        for (int r = 0; r < 4; ++r) {
          int row = wv * 16 + quad * 4 + r;
          posacc[r] += po[r] * sc + mv + se[(size_t)(b0 + row) * 29 + l16];
        }
      }
    }
  } // e

  // ================= final writes: mean over ensembles =================
  if (wv < 4 && l16 < 13) {
    #pragma unroll
    for (int r = 0; r < 4; ++r) {
      int row = wv * 16 + quad * 4 + r;
      out[(size_t)(b0 + row) * 29 + l16] = 0.25f * posacc[r];
    }
  }
  for (int i = tid; i < 64 * 16; i += 512) {
    int t = i >> 4, k = i & 15;
    out[(size_t)(b0 + t) * 29 + 13 + k] = 0.25f * legacc[t][k];
  }
}

// ---------------- launch ----------------------------------------------------
extern "C" void kernel_launch(void* const* d_in, const int* in_sizes, int n_in,
                              void* d_out, int out_size, void* d_ws, size_t ws_size,
                              hipStream_t stream) {
  const float* state = (const float*)d_in[0];
  const float* act = (const float*)d_in[1];
  const float* wl0 = (const float*)d_in[2];
  const float* bl0 = (const float*)d_in[3];
  const float* wl1 = (const float*)d_in[4];
  const float* bl1 = (const float*)d_in[5];
  const float* wl2 = (const float*)d_in[6];
  const float* bl2 = (const float*)d_in[7];
  const float* wp0 = (const float*)d_in[8];
  const float* bp0 = (const float*)d_in[9];
  const float* wp1 = (const float*)d_in[10];
  const float* bp1 = (const float*)d_in[11];
  const float* wp2 = (const float*)d_in[12];
  const float* bp2 = (const float*)d_in[13];
  const float* mu_leg = (const float*)d_in[14];
  const float* sigma_leg = (const float*)d_in[15];
  const float* mu_pose = (const float*)d_in[16];
  const float* sigma_pose = (const float*)d_in[17];
  const float* mu_t_leg = (const float*)d_in[18];
  const float* sigma_t_leg = (const float*)d_in[19];
  const float* mu_t_pose = (const float*)d_in[20];
  const float* sigma_t_pose = (const float*)d_in[21];
  float* out = (float*)d_out;

  char* ws = (char*)d_ws;
  __bf16* WL0p = (__bf16*)(ws);
  __bf16* WL1p = (__bf16*)(ws + 131072);
  __bf16* WL2p = (__bf16*)(ws + 2228224);
  __bf16* WP0p = (__bf16*)(ws + 2293760);
  __bf16* WP1p = (__bf16*)(ws + 2424832);
  __bf16* WP2p = (__bf16*)(ws + 4521984);
  float* bl0f = (float*)(ws + 4587520);
  float* bp0f = (float*)(ws + 4595712);

  prep_kernel<<<512, 256, 0, stream>>>(wl0, wl1, wl2, wp0, wp1, wp2, bl0, bp0,
                                       mu_leg, sigma_leg, mu_pose, sigma_pose,
                                       WL0p, WL1p, WL2p, WP0p, WP1p, WP2p,
                                       bl0f, bp0f);
  fused_kernel<<<256, 512, 0, stream>>>(state, act, bl1, bl2, bp1, bp2,
                                        mu_t_leg, sigma_t_leg, mu_t_pose, sigma_t_pose,
                                        WL0p, WL1p, WL2p, WP0p, WP1p, WP2p,
                                        bl0f, bp0f, out);
}